// Round 1
// 2347.538 us; speedup vs baseline: 3.3774x; 3.3774x over previous
//
#include <hip/hip_runtime.h>

typedef short v8s __attribute__((ext_vector_type(8)));
typedef float v4f __attribute__((ext_vector_type(4)));

#define S_LEN 1024
#define NH    128
#define DM    7168
#define QL    1536
#define KVL   512
#define DQd   192
#define DVd   128
#define QDIM  (NH * DQd)   // 24576
#define VDIM  (NH * DVd)   // 16384

__device__ __forceinline__ float bf2f(unsigned short u) {
  union { unsigned int i; float f; } x; x.i = ((unsigned int)u) << 16; return x.f;
}
__device__ __forceinline__ unsigned short f2bf(float f) {
  union { float f; unsigned int i; } x; x.f = f;
  unsigned int r = x.i + 0x7fffu + ((x.i >> 16) & 1u);
  return (unsigned short)(r >> 16);
}
__device__ __forceinline__ v8s cvt8pair(v4f f0, v4f f1) {
  v8s r; unsigned short* u = (unsigned short*)&r;
#pragma unroll
  for (int i = 0; i < 4; i++) { u[i] = f2bf(f0[i]); u[4 + i] = f2bf(f1[i]); }
  return r;
}

// Swizzled byte offset within a [128 rows x 64 bf16] LDS tile (row = 128 B
// = 8 x 16B slots). XOR the slot index with row&7 so that a 16-lane column
// read (rows r..r+15, fixed slot) spreads over all 8 slots = all 32 banks
// (2 rows/slot = free 2-way). Applied identically on write and read.
__device__ __forceinline__ int swz_off(int row, int slot) {
  return row * 128 + ((slot ^ (row & 7)) << 4);
}

// f32 -> bf16 (RNE), 8 elems/thread
__global__ void cvt_bf16_kernel(const float* __restrict__ in,
                                unsigned short* __restrict__ out, int n8) {
  int i = blockIdx.x * blockDim.x + threadIdx.x;
  if (i >= n8) return;
  v4f f0 = *(const v4f*)(in + (size_t)i * 8);
  v4f f1 = *(const v4f*)(in + (size_t)i * 8 + 4);
  *(v8s*)(out + (size_t)i * 8) = cvt8pair(f0, f1);
}

// C[M,N] = A[M,K](bf16) @ W[N,K](f32)^T.  Tile 128x128, BK=64.
// Block 256 thr = 4 waves (2x2), each wave owns 64x64 = 4x4 MFMA fragments.
// A,B staged through registers into swizzled LDS; next K-tile loads issued
// before the MFMA block so global latency hides under compute.
// grid.x = N/128, grid.y = M/128; K % 64 == 0.
template<bool CF32>
__global__ __launch_bounds__(256) void gemm_tile(
    const unsigned short* __restrict__ A, int lda,
    const float* __restrict__ W, int ldw,
    void* __restrict__ Cv, int ldc, int K)
{
  __shared__ __align__(16) unsigned short As[128 * 64];
  __shared__ __align__(16) unsigned short Bs[128 * 64];

  const int t    = threadIdx.x;
  const int lane = t & 63;
  const int wave = t >> 6;
  const int r15  = lane & 15;
  const int quad = lane >> 4;
  const int wm = wave >> 1, wn = wave & 1;
  const int mb = blockIdx.y * 128;
  const int nb = blockIdx.x * 128;

  // staging: pass p covers rows [p*32, p*32+32), 8 threads (16B slots) per row
  const int srow  = t >> 3;   // 0..31
  const int sslot = t & 7;    // 16B slot within a 128B row

  const unsigned short* aptr = A + (size_t)(mb + srow) * lda + sslot * 8;
  const float*          wptr = W + (size_t)(nb + srow) * ldw + sslot * 8;
  const size_t a32 = (size_t)32 * lda;
  const size_t w32 = (size_t)32 * ldw;

  v4f acc[4][4];
#pragma unroll
  for (int i = 0; i < 4; i++)
#pragma unroll
    for (int j = 0; j < 4; j++) acc[i][j] = (v4f){0.f, 0.f, 0.f, 0.f};

  v8s stA[4];
  v4f stB[8];
#pragma unroll
  for (int p = 0; p < 4; p++) stA[p] = *(const v8s*)(aptr + p * a32);
#pragma unroll
  for (int p = 0; p < 4; p++) {
    stB[2 * p]     = *(const v4f*)(wptr + p * w32);
    stB[2 * p + 1] = *(const v4f*)(wptr + p * w32 + 4);
  }

  for (int k0 = 0; k0 < K; k0 += 64) {
    __syncthreads();   // previous tile's compute done; safe to overwrite LDS
#pragma unroll
    for (int p = 0; p < 4; p++)
      *(v8s*)((char*)As + swz_off(p * 32 + srow, sslot)) = stA[p];
#pragma unroll
    for (int p = 0; p < 4; p++)
      *(v8s*)((char*)Bs + swz_off(p * 32 + srow, sslot)) =
          cvt8pair(stB[2 * p], stB[2 * p + 1]);
    __syncthreads();   // tile visible to all waves

    if (k0 + 64 < K) {  // prefetch next K-tile; stays in flight under MFMA
#pragma unroll
      for (int p = 0; p < 4; p++)
        stA[p] = *(const v8s*)(aptr + p * a32 + k0 + 64);
#pragma unroll
      for (int p = 0; p < 4; p++) {
        stB[2 * p]     = *(const v4f*)(wptr + p * w32 + k0 + 64);
        stB[2 * p + 1] = *(const v4f*)(wptr + p * w32 + k0 + 64 + 4);
      }
    }

#pragma unroll
    for (int kk = 0; kk < 2; kk++) {
      const int cslot = kk * 4 + quad;   // k-slice 16B slot (k = kk*32 + quad*8)
      v8s af[4], bf[4];
#pragma unroll
      for (int fm = 0; fm < 4; fm++)
        af[fm] = *(const v8s*)((char*)As + swz_off(wm * 64 + fm * 16 + r15, cslot));
#pragma unroll
      for (int fn = 0; fn < 4; fn++)
        bf[fn] = *(const v8s*)((char*)Bs + swz_off(wn * 64 + fn * 16 + r15, cslot));
#pragma unroll
      for (int fm = 0; fm < 4; fm++)
#pragma unroll
        for (int fn = 0; fn < 4; fn++)
          acc[fm][fn] = __builtin_amdgcn_mfma_f32_16x16x32_bf16(
              af[fm], bf[fn], acc[fm][fn], 0, 0, 0);
    }
  }

  // epilogue: C col = lane&15, row = quad*4 + r (same convention as verified)
  const int mrow = mb + wm * 64 + quad * 4;
  const int ncol = nb + wn * 64 + r15;
#pragma unroll
  for (int fm = 0; fm < 4; fm++) {
#pragma unroll
    for (int r = 0; r < 4; r++) {
      const size_t crow = (size_t)(mrow + fm * 16 + r) * ldc + ncol;
      if constexpr (CF32) {
        float* C = (float*)Cv;
#pragma unroll
        for (int fn = 0; fn < 4; fn++) C[crow + fn * 16] = acc[fm][fn][r];
      } else {
        unsigned short* C = (unsigned short*)Cv;
#pragma unroll
        for (int fn = 0; fn < 4; fn++) C[crow + fn * 16] = f2bf(acc[fm][fn][r]);
      }
    }
  }
}

// In-place RoPE on q (cols 128..191 of each 192-col head) and k (bf16 ws).
// Pair i in [0,32): angle = pos * 10000^(-((2i) mod 32)/32).
__global__ void rope_kernel(unsigned short* __restrict__ q,
                            unsigned short* __restrict__ k)
{
  int idx = blockIdx.x * blockDim.x + threadIdx.x;  // S*NH*32 = 4194304
  int i = idx & 31;
  int h = (idx >> 5) & (NH - 1);
  int s = idx >> 12;
  int j = (2 * i) & 31;
  float freq = powf(10000.0f, -(float)j / 32.0f);
  float ang = (float)s * freq;
  float c = cosf(ang), sn = sinf(ang);
  size_t base = (size_t)s * QDIM + h * DQd + 128 + 2 * i;

  float t0 = bf2f(q[base]), t1 = bf2f(q[base + 1]);
  q[base]     = f2bf(t0 * c - t1 * sn);
  q[base + 1] = f2bf(t0 * sn + t1 * c);

  t0 = bf2f(k[base]); t1 = bf2f(k[base + 1]);
  k[base]     = f2bf(t0 * c - t1 * sn);
  k[base + 1] = f2bf(t0 * sn + t1 * c);
}

// Fused attention for one (head, 16 q-rows) tile. Full (non-causal) softmax.
// Two-pass (rowmax then exp+rowsum) so scores live only in registers;
// P stored bf16 in LDS; PV via MFMA with V staged through LDS.
// grid: (S/16, NH), block 256 (4 waves).
__global__ __launch_bounds__(256) void attn_kernel(
    const unsigned short* __restrict__ qb,
    const unsigned short* __restrict__ kb,
    const unsigned short* __restrict__ vb,
    unsigned short* __restrict__ ao)
{
  __shared__ unsigned short p_lds[16][1048];   // P tile, stride 1048 (bank spread)
  __shared__ unsigned short v_lds[64][130];    // V chunk, stride 130
  __shared__ float redbuf[4][16];
  __shared__ float rowmax[16];
  __shared__ float rowinv[16];

  const int h  = blockIdx.y;
  const int q0 = blockIdx.x * 16;
  const int t = threadIdx.x;
  const int lane = t & 63;
  const int wave = t >> 6;
  const int r15  = lane & 15;
  const int quad = lane >> 4;
  const float scale = 0.07216878364870323f;  // 1/sqrt(192)

  // Hoisted Q fragments (A-operand: row = lane&15, k = quad*8 + j)
  v8s afr[6];
  {
    const unsigned short* qrow = qb + (size_t)(q0 + r15) * QDIM + h * DQd + quad * 8;
#pragma unroll
    for (int kk = 0; kk < 6; kk++) afr[kk] = *(const v8s*)(qrow + kk * 32);
  }

  // ---- Pass 1: row maxima ----
  float vmax[4] = {-1e30f, -1e30f, -1e30f, -1e30f};
  for (int st = wave; st < 64; st += 4) {
    const int k0 = st * 16;
    const unsigned short* krow = kb + (size_t)(k0 + r15) * QDIM + h * DQd + quad * 8;
    v4f acc = {0.f, 0.f, 0.f, 0.f};
#pragma unroll
    for (int kk = 0; kk < 6; kk++) {
      v8s b = *(const v8s*)(krow + kk * 32);
      acc = __builtin_amdgcn_mfma_f32_16x16x32_bf16(afr[kk], b, acc, 0, 0, 0);
    }
#pragma unroll
    for (int r = 0; r < 4; r++) vmax[r] = fmaxf(vmax[r], acc[r]);
  }
#pragma unroll
  for (int mk = 1; mk < 16; mk <<= 1) {
#pragma unroll
    for (int r = 0; r < 4; r++) vmax[r] = fmaxf(vmax[r], __shfl_xor(vmax[r], mk));
  }
  if (r15 == 0) {
#pragma unroll
    for (int r = 0; r < 4; r++) redbuf[wave][quad * 4 + r] = vmax[r];
  }
  __syncthreads();
  if (t < 16) {
    float m = fmaxf(fmaxf(redbuf[0][t], redbuf[1][t]),
                    fmaxf(redbuf[2][t], redbuf[3][t]));
    rowmax[t] = m * scale;
  }
  __syncthreads();

  // ---- Pass 2: recompute scores, exp, store P (bf16), row sums ----
  float mrow[4];
#pragma unroll
  for (int r = 0; r < 4; r++) mrow[r] = rowmax[quad * 4 + r];
  float vsum[4] = {0.f, 0.f, 0.f, 0.f};
  for (int st = wave; st < 64; st += 4) {
    const int k0 = st * 16;
    const unsigned short* krow = kb + (size_t)(k0 + r15) * QDIM + h * DQd + quad * 8;
    v4f acc = {0.f, 0.f, 0.f, 0.f};
#pragma unroll
    for (int kk = 0; kk < 6; kk++) {
      v8s b = *(const v8s*)(krow + kk * 32);
      acc = __builtin_amdgcn_mfma_f32_16x16x32_bf16(afr[kk], b, acc, 0, 0, 0);
    }
#pragma unroll
    for (int r = 0; r < 4; r++) {
      float p = __expf(acc[r] * scale - mrow[r]);
      unsigned short pb = f2bf(p);
      p_lds[quad * 4 + r][k0 + r15] = pb;
      vsum[r] += bf2f(pb);   // sum the rounded value PV will actually use
    }
  }
#pragma unroll
  for (int mk = 1; mk < 16; mk <<= 1) {
#pragma unroll
    for (int r = 0; r < 4; r++) vsum[r] += __shfl_xor(vsum[r], mk);
  }
  if (r15 == 0) {
#pragma unroll
    for (int r = 0; r < 4; r++) redbuf[wave][quad * 4 + r] = vsum[r];
  }
  __syncthreads();
  if (t < 16) {
    rowinv[t] = 1.0f / (redbuf[0][t] + redbuf[1][t] + redbuf[2][t] + redbuf[3][t]);
  }

  // ---- Phase C: O = P @ V via MFMA, V staged in LDS (16 chunks of 64 k) ----
  v4f oacc0 = {0.f, 0.f, 0.f, 0.f};
  v4f oacc1 = {0.f, 0.f, 0.f, 0.f};
  for (int c = 0; c < 16; c++) {
    __syncthreads();
    // load V chunk [64 k][128 d] cooperatively, 4B at a time
    for (int e = t; e < 64 * 64; e += 256) {
      int kk = e >> 6;
      int d2 = (e & 63) * 2;
      *(unsigned int*)(&v_lds[kk][d2]) =
          *(const unsigned int*)(vb + (size_t)(c * 64 + kk) * VDIM + h * DVd + d2);
    }
    __syncthreads();
#pragma unroll
    for (int ks = 0; ks < 2; ks++) {
      const int kb2 = c * 64 + ks * 32 + quad * 8;
      v8s af = *(const v8s*)(&p_lds[r15][kb2]);
      const int kl = ks * 32 + quad * 8;
#pragma unroll
      for (int ds = 0; ds < 2; ds++) {
        const int d0 = (wave * 2 + ds) * 16;
        v8s bfr;
        unsigned short* bp = (unsigned short*)&bfr;
#pragma unroll
        for (int j = 0; j < 8; j++) bp[j] = v_lds[kl + j][d0 + r15];
        if (ds == 0) oacc0 = __builtin_amdgcn_mfma_f32_16x16x32_bf16(af, bfr, oacc0, 0, 0, 0);
        else         oacc1 = __builtin_amdgcn_mfma_f32_16x16x32_bf16(af, bfr, oacc1, 0, 0, 0);
      }
    }
  }

  // epilogue: C layout col = lane&15, row = quad*4 + r
#pragma unroll
  for (int ds = 0; ds < 2; ds++) {
    const int d0 = (wave * 2 + ds) * 16;
#pragma unroll
    for (int r = 0; r < 4; r++) {
      const int qi = quad * 4 + r;
      float v = (ds == 0 ? oacc0[r] : oacc1[r]) * rowinv[qi];
      ao[(size_t)(q0 + qi) * VDIM + h * DVd + d0 + r15] = f2bf(v);
    }
  }
}

extern "C" void kernel_launch(void* const* d_in, const int* in_sizes, int n_in,
                              void* d_out, int out_size, void* d_ws, size_t ws_size,
                              hipStream_t stream) {
  const float* hidden = (const float*)d_in[0];
  const float* Wqa  = (const float*)d_in[1];
  const float* Wkva = (const float*)d_in[2];
  const float* Wqb  = (const float*)d_in[3];
  const float* Wkb  = (const float*)d_in[4];
  const float* Wvb  = (const float*)d_in[5];
  const float* Wo   = (const float*)d_in[6];
  float* out = (float*)d_out;

  // bf16 intermediates in workspace
  unsigned short* ws  = (unsigned short*)d_ws;
  unsigned short* lat = ws;                                   // [1024, 2048]
  unsigned short* qb  = lat + (size_t)S_LEN * 2048;           // [1024, 24576]
  unsigned short* kb  = qb  + (size_t)S_LEN * QDIM;           // [1024, 24576]
  unsigned short* vb  = kb  + (size_t)S_LEN * QDIM;           // [1024, 16384]
  unsigned short* ao  = vb  + (size_t)S_LEN * VDIM;           // [1024, 16384]
  unsigned short* hb  = ao  + (size_t)S_LEN * VDIM;           // [1024, 7168] bf16 hidden

  dim3 blk(256);

  // hidden -> bf16 once (A operand of the latent gemms)
  cvt_bf16_kernel<<<(S_LEN * DM / 8) / 256, blk, 0, stream>>>(hidden, hb, S_LEN * DM / 8);

  // latent projections: lat[:, :1536] = hidden @ Wqa^T ; lat[:, 1536:] = hidden @ Wkva^T
  gemm_tile<false><<<dim3(QL / 128, S_LEN / 128), blk, 0, stream>>>(
      hb, DM, Wqa, DM, lat, 2048, DM);
  gemm_tile<false><<<dim3(KVL / 128, S_LEN / 128), blk, 0, stream>>>(
      hb, DM, Wkva, DM, lat + QL, 2048, DM);

  // up-projections (A = bf16 latent, W = f32)
  gemm_tile<false><<<dim3(QDIM / 128, S_LEN / 128), blk, 0, stream>>>(
      lat, 2048, Wqb, QL, qb, QDIM, QL);
  gemm_tile<false><<<dim3(QDIM / 128, S_LEN / 128), blk, 0, stream>>>(
      lat + QL, 2048, Wkb, KVL, kb, QDIM, KVL);
  gemm_tile<false><<<dim3(VDIM / 128, S_LEN / 128), blk, 0, stream>>>(
      lat + QL, 2048, Wvb, KVL, vb, VDIM, KVL);

  // RoPE on q and k rope-halves
  rope_kernel<<<(S_LEN * NH * 32) / 256, blk, 0, stream>>>(qb, kb);

  // fused attention
  attn_kernel<<<dim3(S_LEN / 16, NH), blk, 0, stream>>>(qb, kb, vb, ao);

  // output projection -> d_out (f32)
  gemm_tile<true><<<dim3(DM / 128, S_LEN / 128), blk, 0, stream>>>(
      ao, VDIM, Wo, VDIM, out, DM, VDIM);
}

// Round 2
// 2122.519 us; speedup vs baseline: 3.7354x; 1.1060x over previous
//
#include <hip/hip_runtime.h>

typedef short v8s __attribute__((ext_vector_type(8)));
typedef float v4f __attribute__((ext_vector_type(4)));

#define S_LEN 1024
#define NH    128
#define DM    7168
#define QL    1536
#define KVL   512
#define DQd   192
#define DVd   128
#define QDIM  (NH * DQd)   // 24576
#define VDIM  (NH * DVd)   // 16384

__device__ __forceinline__ float bf2f(unsigned short u) {
  union { unsigned int i; float f; } x; x.i = ((unsigned int)u) << 16; return x.f;
}
__device__ __forceinline__ unsigned short f2bf(float f) {
  union { float f; unsigned int i; } x; x.f = f;
  unsigned int r = x.i + 0x7fffu + ((x.i >> 16) & 1u);
  return (unsigned short)(r >> 16);
}
__device__ __forceinline__ v8s cvt8pair(v4f f0, v4f f1) {
  v8s r; unsigned short* u = (unsigned short*)&r;
#pragma unroll
  for (int i = 0; i < 4; i++) { u[i] = f2bf(f0[i]); u[4 + i] = f2bf(f1[i]); }
  return r;
}

// Swizzled byte offset within a [128 rows x 64 bf16] LDS tile (row = 128 B
// = 8 x 16B slots). XOR the slot index with row&7 so a 16-lane column read
// spreads over all 8 slots = all 32 banks. Applied identically write+read.
__device__ __forceinline__ int swz_off(int row, int slot) {
  return row * 128 + ((slot ^ (row & 7)) << 4);
}

// f32 -> bf16 (RNE), 8 elems/thread
__global__ void cvt_bf16_kernel(const float* __restrict__ in,
                                unsigned short* __restrict__ out, int n8) {
  int i = blockIdx.x * blockDim.x + threadIdx.x;
  if (i >= n8) return;
  v4f f0 = *(const v4f*)(in + (size_t)i * 8);
  v4f f1 = *(const v4f*)(in + (size_t)i * 8 + 4);
  *(v8s*)(out + (size_t)i * 8) = cvt8pair(f0, f1);
}

// vb [S][VDIM] u16 -> vt [VDIM][S] u16.  Reads coalesced (lane = e),
// writes 64 B contiguous per lane.  grid (VDIM/256, S/32), block 256.
__global__ __launch_bounds__(256) void transpose_kernel(
    const unsigned short* __restrict__ in, unsigned short* __restrict__ out)
{
  const int lane = threadIdx.x & 63;
  const int wave = threadIdx.x >> 6;
  const int e  = blockIdx.x * 256 + wave * 64 + lane;
  const int s0 = blockIdx.y * 32;
  unsigned short tmp[32];
#pragma unroll
  for (int j = 0; j < 32; j++)
    tmp[j] = in[(size_t)(s0 + j) * VDIM + e];
  unsigned short* op = out + (size_t)e * S_LEN + s0;
#pragma unroll
  for (int j = 0; j < 4; j++)
    *(v8s*)(op + j * 8) = *(v8s*)(tmp + j * 8);
}

// C[M,N] = A[M,K](bf16) @ W[N,K](f32)^T.  Tile 128x128, BK=64.
// Block 256 thr = 4 waves (2x2), each wave owns 64x64 = 4x4 MFMA fragments.
// A,B staged through registers into swizzled LDS; next K-tile loads issued
// before the MFMA block so global latency hides under compute.
template<bool CF32>
__global__ __launch_bounds__(256) void gemm_tile(
    const unsigned short* __restrict__ A, int lda,
    const float* __restrict__ W, int ldw,
    void* __restrict__ Cv, int ldc, int K)
{
  __shared__ __align__(16) unsigned short As[128 * 64];
  __shared__ __align__(16) unsigned short Bs[128 * 64];

  const int t    = threadIdx.x;
  const int lane = t & 63;
  const int wave = t >> 6;
  const int r15  = lane & 15;
  const int quad = lane >> 4;
  const int wm = wave >> 1, wn = wave & 1;
  const int mb = blockIdx.y * 128;
  const int nb = blockIdx.x * 128;

  const int srow  = t >> 3;   // 0..31
  const int sslot = t & 7;    // 16B slot within a 128B row

  const unsigned short* aptr = A + (size_t)(mb + srow) * lda + sslot * 8;
  const float*          wptr = W + (size_t)(nb + srow) * ldw + sslot * 8;
  const size_t a32 = (size_t)32 * lda;
  const size_t w32 = (size_t)32 * ldw;

  v4f acc[4][4];
#pragma unroll
  for (int i = 0; i < 4; i++)
#pragma unroll
    for (int j = 0; j < 4; j++) acc[i][j] = (v4f){0.f, 0.f, 0.f, 0.f};

  v8s stA[4];
  v4f stB[8];
#pragma unroll
  for (int p = 0; p < 4; p++) stA[p] = *(const v8s*)(aptr + p * a32);
#pragma unroll
  for (int p = 0; p < 4; p++) {
    stB[2 * p]     = *(const v4f*)(wptr + p * w32);
    stB[2 * p + 1] = *(const v4f*)(wptr + p * w32 + 4);
  }

  for (int k0 = 0; k0 < K; k0 += 64) {
    __syncthreads();
#pragma unroll
    for (int p = 0; p < 4; p++)
      *(v8s*)((char*)As + swz_off(p * 32 + srow, sslot)) = stA[p];
#pragma unroll
    for (int p = 0; p < 4; p++)
      *(v8s*)((char*)Bs + swz_off(p * 32 + srow, sslot)) =
          cvt8pair(stB[2 * p], stB[2 * p + 1]);
    __syncthreads();

    if (k0 + 64 < K) {
#pragma unroll
      for (int p = 0; p < 4; p++)
        stA[p] = *(const v8s*)(aptr + p * a32 + k0 + 64);
#pragma unroll
      for (int p = 0; p < 4; p++) {
        stB[2 * p]     = *(const v4f*)(wptr + p * w32 + k0 + 64);
        stB[2 * p + 1] = *(const v4f*)(wptr + p * w32 + k0 + 64 + 4);
      }
    }

#pragma unroll
    for (int kk = 0; kk < 2; kk++) {
      const int cslot = kk * 4 + quad;
      v8s af[4], bfv[4];
#pragma unroll
      for (int fm = 0; fm < 4; fm++)
        af[fm] = *(const v8s*)((char*)As + swz_off(wm * 64 + fm * 16 + r15, cslot));
#pragma unroll
      for (int fn = 0; fn < 4; fn++)
        bfv[fn] = *(const v8s*)((char*)Bs + swz_off(wn * 64 + fn * 16 + r15, cslot));
#pragma unroll
      for (int fm = 0; fm < 4; fm++)
#pragma unroll
        for (int fn = 0; fn < 4; fn++)
          acc[fm][fn] = __builtin_amdgcn_mfma_f32_16x16x32_bf16(
              af[fm], bfv[fn], acc[fm][fn], 0, 0, 0);
    }
  }

  const int mrow = mb + wm * 64 + quad * 4;
  const int ncol = nb + wn * 64 + r15;
#pragma unroll
  for (int fm = 0; fm < 4; fm++) {
#pragma unroll
    for (int r = 0; r < 4; r++) {
      const size_t crow = (size_t)(mrow + fm * 16 + r) * ldc + ncol;
      if constexpr (CF32) {
        float* C = (float*)Cv;
#pragma unroll
        for (int fn = 0; fn < 4; fn++) C[crow + fn * 16] = acc[fm][fn][r];
      } else {
        unsigned short* C = (unsigned short*)Cv;
#pragma unroll
        for (int fn = 0; fn < 4; fn++) C[crow + fn * 16] = f2bf(acc[fm][fn][r]);
      }
    }
  }
}

// In-place RoPE on q (cols 128..191 of each 192-col head) and k (bf16 ws).
__global__ void rope_kernel(unsigned short* __restrict__ q,
                            unsigned short* __restrict__ k)
{
  int idx = blockIdx.x * blockDim.x + threadIdx.x;  // S*NH*32
  int i = idx & 31;
  int h = (idx >> 5) & (NH - 1);
  int s = idx >> 12;
  int j = (2 * i) & 31;
  float freq = powf(10000.0f, -(float)j / 32.0f);
  float ang = (float)s * freq;
  float c = cosf(ang), sn = sinf(ang);
  size_t base = (size_t)s * QDIM + h * DQd + 128 + 2 * i;

  float t0 = bf2f(q[base]), t1 = bf2f(q[base + 1]);
  q[base]     = f2bf(t0 * c - t1 * sn);
  q[base + 1] = f2bf(t0 * sn + t1 * c);

  t0 = bf2f(k[base]); t1 = bf2f(k[base + 1]);
  k[base]     = f2bf(t0 * c - t1 * sn);
  k[base + 1] = f2bf(t0 * sn + t1 * c);
}

// Fused attention for one (head, 16 q-rows) tile. Full (non-causal) softmax.
// Scores kept in registers (sreg[16]) across max and exp passes -> QK^T
// computed ONCE.  PV reads V directly from the pre-transposed vt[VDIM][S]
// (L2-resident per head): each B-fragment is a single per-lane v8s load.
// grid: (S/16, NH), block 256 (4 waves, wave w handles k-tiles w,w+4,...).
__global__ __launch_bounds__(256) void attn_kernel(
    const unsigned short* __restrict__ qb,
    const unsigned short* __restrict__ kb,
    const unsigned short* __restrict__ vt,
    unsigned short* __restrict__ ao)
{
  __shared__ __align__(16) unsigned short p_lds[16][1048];  // P tile bf16
  __shared__ float redbuf[4][16];
  __shared__ float rowmax[16];
  __shared__ float rowinv[16];

  const int h  = blockIdx.y;
  const int q0 = blockIdx.x * 16;
  const int t = threadIdx.x;
  const int lane = t & 63;
  const int wave = t >> 6;
  const int r15  = lane & 15;
  const int quad = lane >> 4;
  const float scale = 0.07216878364870323f;  // 1/sqrt(192)

  // Hoisted Q fragments (A-operand: row = lane&15, k = quad*8 + j)
  v8s afr[6];
  {
    const unsigned short* qrow = qb + (size_t)(q0 + r15) * QDIM + h * DQd + quad * 8;
#pragma unroll
    for (int kk = 0; kk < 6; kk++) afr[kk] = *(const v8s*)(qrow + kk * 32);
  }

  // ---- Pass 1: QK^T once, scores into registers, track row maxima ----
  v4f sreg[16];
  float vmax[4] = {-1e30f, -1e30f, -1e30f, -1e30f};
#pragma unroll
  for (int i = 0; i < 16; i++) {
    const int k0 = (wave + i * 4) * 16;
    const unsigned short* krow = kb + (size_t)(k0 + r15) * QDIM + h * DQd + quad * 8;
    v4f acc = {0.f, 0.f, 0.f, 0.f};
    __builtin_amdgcn_s_setprio(1);
#pragma unroll
    for (int kk = 0; kk < 6; kk++) {
      v8s b = *(const v8s*)(krow + kk * 32);
      acc = __builtin_amdgcn_mfma_f32_16x16x32_bf16(afr[kk], b, acc, 0, 0, 0);
    }
    __builtin_amdgcn_s_setprio(0);
    sreg[i] = acc;
#pragma unroll
    for (int r = 0; r < 4; r++) vmax[r] = fmaxf(vmax[r], acc[r]);
  }
#pragma unroll
  for (int mk = 1; mk < 16; mk <<= 1) {
#pragma unroll
    for (int r = 0; r < 4; r++) vmax[r] = fmaxf(vmax[r], __shfl_xor(vmax[r], mk));
  }
  if (r15 == 0) {
#pragma unroll
    for (int r = 0; r < 4; r++) redbuf[wave][quad * 4 + r] = vmax[r];
  }
  __syncthreads();
  if (t < 16) {
    float m = fmaxf(fmaxf(redbuf[0][t], redbuf[1][t]),
                    fmaxf(redbuf[2][t], redbuf[3][t]));
    rowmax[t] = m * scale;
  }
  __syncthreads();

  // ---- Pass 2: exp from registers, store P (bf16), row sums ----
  float mrow[4];
#pragma unroll
  for (int r = 0; r < 4; r++) mrow[r] = rowmax[quad * 4 + r];
  float vsum[4] = {0.f, 0.f, 0.f, 0.f};
#pragma unroll
  for (int i = 0; i < 16; i++) {
    const int k0 = (wave + i * 4) * 16;
#pragma unroll
    for (int r = 0; r < 4; r++) {
      float p = __expf(sreg[i][r] * scale - mrow[r]);
      unsigned short pb = f2bf(p);
      p_lds[quad * 4 + r][k0 + r15] = pb;
      vsum[r] += bf2f(pb);   // sum the rounded value PV will actually use
    }
  }
#pragma unroll
  for (int mk = 1; mk < 16; mk <<= 1) {
#pragma unroll
    for (int r = 0; r < 4; r++) vsum[r] += __shfl_xor(vsum[r], mk);
  }
  if (r15 == 0) {
#pragma unroll
    for (int r = 0; r < 4; r++) redbuf[wave][quad * 4 + r] = vsum[r];
  }
  __syncthreads();
  if (t < 16) {
    rowinv[t] = 1.0f / (redbuf[0][t] + redbuf[1][t] + redbuf[2][t] + redbuf[3][t]);
  }
  __syncthreads();   // p_lds + rowinv ready for all waves

  // ---- Phase C: O = P @ V via MFMA, V fragments straight from vt ----
  v4f oacc0 = {0.f, 0.f, 0.f, 0.f};
  v4f oacc1 = {0.f, 0.f, 0.f, 0.f};
  const unsigned short* vbase = vt + (size_t)h * DVd * S_LEN;
  const int d0a = (wave * 2) * 16 + r15;
  const int d0b = (wave * 2 + 1) * 16 + r15;
  for (int kt = 0; kt < 32; kt++) {
    const int kk = kt * 32 + quad * 8;
    v8s af  = *(const v8s*)(&p_lds[r15][kk]);
    v8s bf0 = *(const v8s*)(vbase + (size_t)d0a * S_LEN + kk);
    v8s bf1 = *(const v8s*)(vbase + (size_t)d0b * S_LEN + kk);
    __builtin_amdgcn_s_setprio(1);
    oacc0 = __builtin_amdgcn_mfma_f32_16x16x32_bf16(af, bf0, oacc0, 0, 0, 0);
    oacc1 = __builtin_amdgcn_mfma_f32_16x16x32_bf16(af, bf1, oacc1, 0, 0, 0);
    __builtin_amdgcn_s_setprio(0);
  }

  // epilogue: C layout col = lane&15, row = quad*4 + r
#pragma unroll
  for (int ds = 0; ds < 2; ds++) {
    const int d0 = (wave * 2 + ds) * 16;
#pragma unroll
    for (int r = 0; r < 4; r++) {
      const int qi = quad * 4 + r;
      float v = (ds == 0 ? oacc0[r] : oacc1[r]) * rowinv[qi];
      ao[(size_t)(q0 + qi) * VDIM + h * DVd + d0 + r15] = f2bf(v);
    }
  }
}

extern "C" void kernel_launch(void* const* d_in, const int* in_sizes, int n_in,
                              void* d_out, int out_size, void* d_ws, size_t ws_size,
                              hipStream_t stream) {
  const float* hidden = (const float*)d_in[0];
  const float* Wqa  = (const float*)d_in[1];
  const float* Wkva = (const float*)d_in[2];
  const float* Wqb  = (const float*)d_in[3];
  const float* Wkb  = (const float*)d_in[4];
  const float* Wvb  = (const float*)d_in[5];
  const float* Wo   = (const float*)d_in[6];
  float* out = (float*)d_out;

  // bf16 intermediates in workspace
  unsigned short* ws  = (unsigned short*)d_ws;
  unsigned short* lat = ws;                                   // [1024, 2048]
  unsigned short* qb  = lat + (size_t)S_LEN * 2048;           // [1024, 24576]
  unsigned short* kb  = qb  + (size_t)S_LEN * QDIM;           // [1024, 24576]
  unsigned short* vb  = kb  + (size_t)S_LEN * QDIM;           // [1024, 16384]
  unsigned short* ao  = vb  + (size_t)S_LEN * VDIM;           // [1024, 16384]
  unsigned short* hb  = ao  + (size_t)S_LEN * VDIM;           // [1024, 7168]
  unsigned short* vt  = hb  + (size_t)S_LEN * DM;             // [16384, 1024] V^T

  dim3 blk(256);

  // hidden -> bf16 once (A operand of the latent gemms)
  cvt_bf16_kernel<<<(S_LEN * DM / 8) / 256, blk, 0, stream>>>(hidden, hb, S_LEN * DM / 8);

  // latent projections
  gemm_tile<false><<<dim3(QL / 128, S_LEN / 128), blk, 0, stream>>>(
      hb, DM, Wqa, DM, lat, 2048, DM);
  gemm_tile<false><<<dim3(KVL / 128, S_LEN / 128), blk, 0, stream>>>(
      hb, DM, Wkva, DM, lat + QL, 2048, DM);

  // up-projections (A = bf16 latent, W = f32)
  gemm_tile<false><<<dim3(QDIM / 128, S_LEN / 128), blk, 0, stream>>>(
      lat, 2048, Wqb, QL, qb, QDIM, QL);
  gemm_tile<false><<<dim3(QDIM / 128, S_LEN / 128), blk, 0, stream>>>(
      lat + QL, 2048, Wkb, KVL, kb, QDIM, KVL);
  gemm_tile<false><<<dim3(VDIM / 128, S_LEN / 128), blk, 0, stream>>>(
      lat + QL, 2048, Wvb, KVL, vb, VDIM, KVL);

  // RoPE on q and k rope-halves
  rope_kernel<<<(S_LEN * NH * 32) / 256, blk, 0, stream>>>(qb, kb);

  // V -> V^T (per-head L2-resident operand for PV)
  transpose_kernel<<<dim3(VDIM / 256, S_LEN / 32), blk, 0, stream>>>(vb, vt);

  // fused attention
  attn_kernel<<<dim3(S_LEN / 16, NH), blk, 0, stream>>>(qb, kb, vt, ao);

  // output projection -> d_out (f32)
  gemm_tile<true><<<dim3(DM / 128, S_LEN / 128), blk, 0, stream>>>(
      ao, VDIM, Wo, VDIM, out, DM, VDIM);
}